// Round 8
// baseline (145.749 us; speedup 1.0000x reference)
//
#include <hip/hip_runtime.h>
#include <hip/hip_bf16.h>

#define TOKEN_DIM 16
#define RANGES 3       // LDS 133KB/block, 1 block/CU; scan work 3E (r7: scan term ~2.3us/range)
#define MAX_C  80      // grid = 3*C = 240; 30 blocks/XCD <= 32 CUs (no 2x tail)
#define NXCD   8

typedef float floatx4 __attribute__((ext_vector_type(4)));

// Phase 1: block (chunk c, range r) scans edge chunk c, accumulates
// s[row] += x[col] for its row-range via exec-masked LDS atomics.
// r8 change: 16 edges/thread/iteration (was 8) - phase1 is LATENCY-bound
// (r7: VALU 8%, HBM 10%, occ 35%), so double the in-flight gathers per wave
// to compensate the 1-block/CU occupancy. One vmcnt window covers 16 gathers.
__global__ __launch_bounds__(1024, 4)
void nit_phase1(const int* __restrict__ row, const int* __restrict__ col,
                const float* __restrict__ x,
                unsigned short* __restrict__ partial,   // [C][N] bf16 bits
                int N, long long E, int chunkE, int RS, int C) {
    extern __shared__ float acc[];          // RS floats (133,336 B for RS=33334)
    const int b = blockIdx.x;
    const int k = b % NXCD;                 // physical XCD (round-robin heuristic)
    const int s = b / NXCD;
    const int r = s % RANGES;
    const int c = k + NXCD * (s / RANGES);  // chunk: c % 8 == k (FETCH 126->27MB, r1/r4)
    if (c >= C) return;                     // block-uniform, before any barrier

    const int base = r * RS;
    int cnt = N - base; if (cnt > RS) cnt = RS; if (cnt < 0) cnt = 0;
    const int t = threadIdx.x, nt = blockDim.x;
    const unsigned ucnt = (unsigned)cnt;

    for (int j = t; j < cnt; j += nt) acc[j] = 0.0f;
    __syncthreads();

    long long i0 = (long long)c * chunkE;
    long long i1 = i0 + chunkE; if (i1 > E) i1 = E;
    long long len = (i1 > i0) ? (i1 - i0) : 0;
    long long ngrp = len >> 4;              // 16 edges/group (i0 is 16-aligned)

    long long g = t;
    int4 ra0, ra1, ra2, ra3, ca0, ca1, ca2, ca3;
    if (g < ngrp) {
        const long long idx = i0 + (g << 4);
        ra0 = *reinterpret_cast<const int4*>(row + idx);
        ra1 = *reinterpret_cast<const int4*>(row + idx + 4);
        ra2 = *reinterpret_cast<const int4*>(row + idx + 8);
        ra3 = *reinterpret_cast<const int4*>(row + idx + 12);
        ca0 = *reinterpret_cast<const int4*>(col + idx);
        ca1 = *reinterpret_cast<const int4*>(col + idx + 4);
        ca2 = *reinterpret_cast<const int4*>(col + idx + 8);
        ca3 = *reinterpret_cast<const int4*>(col + idx + 12);
    }
    while (g < ngrp) {
        const unsigned d0  = (unsigned)(ra0.x - base);
        const unsigned d1  = (unsigned)(ra0.y - base);
        const unsigned d2  = (unsigned)(ra0.z - base);
        const unsigned d3  = (unsigned)(ra0.w - base);
        const unsigned d4  = (unsigned)(ra1.x - base);
        const unsigned d5  = (unsigned)(ra1.y - base);
        const unsigned d6  = (unsigned)(ra1.z - base);
        const unsigned d7  = (unsigned)(ra1.w - base);
        const unsigned d8  = (unsigned)(ra2.x - base);
        const unsigned d9  = (unsigned)(ra2.y - base);
        const unsigned d10 = (unsigned)(ra2.z - base);
        const unsigned d11 = (unsigned)(ra2.w - base);
        const unsigned d12 = (unsigned)(ra3.x - base);
        const unsigned d13 = (unsigned)(ra3.y - base);
        const unsigned d14 = (unsigned)(ra3.z - base);
        const unsigned d15 = (unsigned)(ra3.w - base);

        // 1) 16 exec-masked gathers, issued back-to-back (one vmcnt window)
        float v0, v1, v2, v3, v4, v5, v6, v7, v8, v9, v10, v11, v12, v13, v14, v15;
        if (d0  < ucnt) v0  = x[ca0.x];
        if (d1  < ucnt) v1  = x[ca0.y];
        if (d2  < ucnt) v2  = x[ca0.z];
        if (d3  < ucnt) v3  = x[ca0.w];
        if (d4  < ucnt) v4  = x[ca1.x];
        if (d5  < ucnt) v5  = x[ca1.y];
        if (d6  < ucnt) v6  = x[ca1.z];
        if (d7  < ucnt) v7  = x[ca1.w];
        if (d8  < ucnt) v8  = x[ca2.x];
        if (d9  < ucnt) v9  = x[ca2.y];
        if (d10 < ucnt) v10 = x[ca2.z];
        if (d11 < ucnt) v11 = x[ca2.w];
        if (d12 < ucnt) v12 = x[ca3.x];
        if (d13 < ucnt) v13 = x[ca3.y];
        if (d14 < ucnt) v14 = x[ca3.z];
        if (d15 < ucnt) v15 = x[ca3.w];

        // 2) prefetch next group's indices (stay in flight across the atomics)
        const long long gn = g + nt;
        int4 rb0, rb1, rb2, rb3, cb0, cb1, cb2, cb3;
        if (gn < ngrp) {
            const long long idx = i0 + (gn << 4);
            rb0 = *reinterpret_cast<const int4*>(row + idx);
            rb1 = *reinterpret_cast<const int4*>(row + idx + 4);
            rb2 = *reinterpret_cast<const int4*>(row + idx + 8);
            rb3 = *reinterpret_cast<const int4*>(row + idx + 12);
            cb0 = *reinterpret_cast<const int4*>(col + idx);
            cb1 = *reinterpret_cast<const int4*>(col + idx + 4);
            cb2 = *reinterpret_cast<const int4*>(col + idx + 8);
            cb3 = *reinterpret_cast<const int4*>(col + idx + 12);
        }
        __builtin_amdgcn_sched_barrier(0);  // pin: loads before atomic pass

        // 3) 16 exec-masked LDS atomics
        if (d0  < ucnt) atomicAdd(&acc[d0],  v0);
        if (d1  < ucnt) atomicAdd(&acc[d1],  v1);
        if (d2  < ucnt) atomicAdd(&acc[d2],  v2);
        if (d3  < ucnt) atomicAdd(&acc[d3],  v3);
        if (d4  < ucnt) atomicAdd(&acc[d4],  v4);
        if (d5  < ucnt) atomicAdd(&acc[d5],  v5);
        if (d6  < ucnt) atomicAdd(&acc[d6],  v6);
        if (d7  < ucnt) atomicAdd(&acc[d7],  v7);
        if (d8  < ucnt) atomicAdd(&acc[d8],  v8);
        if (d9  < ucnt) atomicAdd(&acc[d9],  v9);
        if (d10 < ucnt) atomicAdd(&acc[d10], v10);
        if (d11 < ucnt) atomicAdd(&acc[d11], v11);
        if (d12 < ucnt) atomicAdd(&acc[d12], v12);
        if (d13 < ucnt) atomicAdd(&acc[d13], v13);
        if (d14 < ucnt) atomicAdd(&acc[d14], v14);
        if (d15 < ucnt) atomicAdd(&acc[d15], v15);

        ra0 = rb0; ra1 = rb1; ra2 = rb2; ra3 = rb3;
        ca0 = cb0; ca1 = cb1; ca2 = cb2; ca3 = cb3;
        g = gn;
    }
    for (long long idx = i0 + (ngrp << 4) + t; idx < i1; idx += nt) {
        unsigned d = (unsigned)(row[idx] - base);
        if (d < ucnt) atomicAdd(&acc[d], x[col[idx]]);
    }
    __syncthreads();

    // paired bf16 writeback, plain stores (partial stays cached for phase 2)
    unsigned short* dst = partial + (size_t)c * N + base;    // 4B-aligned (N, base even)
    unsigned int* dst2 = reinterpret_cast<unsigned int*>(dst);
    const int cnt2 = cnt >> 1;
    for (int j = t; j < cnt2; j += nt) {
        __hip_bfloat16 ha = __float2bfloat16(acc[2 * j]);
        __hip_bfloat16 hb = __float2bfloat16(acc[2 * j + 1]);
        unsigned int w = (unsigned int)(*reinterpret_cast<unsigned short*>(&ha))
                       | ((unsigned int)(*reinterpret_cast<unsigned short*>(&hb)) << 16);
        dst2[j] = w;
    }
    if ((cnt & 1) && t == 0) {
        __hip_bfloat16 h = __float2bfloat16(acc[cnt - 1]);
        dst[cnt - 1] = *reinterpret_cast<unsigned short*>(&h);
    }
}

// Phase 2 (unchanged, ~<10 us): 256 nodes/block, uint2 (4 bf16) reads,
// C split across 4 wave-groups, LDS reduce, all 256 threads run the MLP.
__global__ __launch_bounds__(256, 8)
void nit_phase2(const float* __restrict__ x,
                const unsigned short* __restrict__ partial,
                const float* __restrict__ w1, const float* __restrict__ b1,
                const float* __restrict__ w2, const float* __restrict__ b2,
                float* __restrict__ out, int N, int C) {
    __shared__ float sw1[TOKEN_DIM * 2];
    __shared__ float sb1[TOKEN_DIM];
    __shared__ float sw2[TOKEN_DIM * TOKEN_DIM];
    __shared__ float sb2[TOKEN_DIM];
    __shared__ float red[4][256];

    const int t = threadIdx.x;
    sw2[t] = w2[t];
    if (t < TOKEN_DIM * 2) sw1[t] = w1[t];
    if (t < TOKEN_DIM) { sb1[t] = b1[t]; sb2[t] = b2[t]; }

    const int lane = t & 63;
    const int grp  = t >> 6;
    const int node0 = blockIdx.x << 8;
    const int n4 = node0 + (lane << 2);

    float s0 = 0.0f, s1 = 0.0f, s2 = 0.0f, s3 = 0.0f;
    if (n4 + 3 < N) {
        const unsigned short* p = partial + n4;
#pragma unroll 4
        for (int c = grp; c < C; c += 4) {
            uint2 u = *reinterpret_cast<const uint2*>(p + (size_t)c * N);  // 8B-aligned
            s0 += __uint_as_float(u.x << 16);
            s1 += __uint_as_float(u.x & 0xffff0000u);
            s2 += __uint_as_float(u.y << 16);
            s3 += __uint_as_float(u.y & 0xffff0000u);
        }
    } else if (n4 < N) {
        for (int c = grp; c < C; c += 4) {
            const unsigned short* p = partial + (size_t)c * N;
            s0 += __uint_as_float(((unsigned)p[n4]) << 16);
            if (n4 + 1 < N) s1 += __uint_as_float(((unsigned)p[n4 + 1]) << 16);
            if (n4 + 2 < N) s2 += __uint_as_float(((unsigned)p[n4 + 2]) << 16);
        }
    }
    floatx4 sv = { s0, s1, s2, s3 };
    *reinterpret_cast<floatx4*>(&red[grp][lane << 2]) = sv;
    __syncthreads();

    const int n = node0 + t;
    if (n < N) {
        const float ssum = red[0][t] + red[1][t] + red[2][t] + red[3][t];
        const float xv = x[n];
        const float lv = xv * ssum;

        float h[TOKEN_DIM];
#pragma unroll
        for (int j = 0; j < TOKEN_DIM; ++j) {
            float v = fmaf(xv, sw1[2 * j], fmaf(lv, sw1[2 * j + 1], sb1[j]));
            h[j] = v > 0.0f ? v : 0.0f;
        }

        float o[TOKEN_DIM];
#pragma unroll
        for (int j = 0; j < TOKEN_DIM; ++j) {
            float v = sb2[j];
#pragma unroll
            for (int kk = 0; kk < TOKEN_DIM; ++kk)
                v = fmaf(h[kk], sw2[j * TOKEN_DIM + kk], v);
            o[j] = v > 0.0f ? v : 0.0f;
        }

        floatx4* op = reinterpret_cast<floatx4*>(out + (size_t)n * TOKEN_DIM);
#pragma unroll
        for (int j = 0; j < 4; ++j) {
            floatx4 w = { o[4 * j], o[4 * j + 1], o[4 * j + 2], o[4 * j + 3] };
            op[j] = w;
        }
    }
}

extern "C" void kernel_launch(void* const* d_in, const int* in_sizes, int n_in,
                              void* d_out, int out_size, void* d_ws, size_t ws_size,
                              hipStream_t stream) {
    const float* x  = (const float*)d_in[0];
    const int*   ei = (const int*)d_in[1];   // [2, E] flat: rows then cols
    const float* w1 = (const float*)d_in[2];
    const float* b1 = (const float*)d_in[3];
    const float* w2 = (const float*)d_in[4];
    const float* b2 = (const float*)d_in[5];
    float* out = (float*)d_out;

    const int N = in_sizes[0];
    const long long E = in_sizes[1] / 2;
    const int* row = ei;
    const int* col = ei + E;

    long long maxC = (long long)(ws_size / ((size_t)N * sizeof(unsigned short)));
    int C = maxC < 1 ? 1 : (maxC > MAX_C ? MAX_C : (int)maxC);
    int RS = ((N + RANGES - 1) / RANGES + 1) & ~1;   // 33334: even -> 4B-aligned slices
    long long ce = (E + C - 1) / C;
    int chunkE = (int)((ce + 15LL) & ~15LL);         // 16-aligned for 16-edge groups

    unsigned short* partial = (unsigned short*)d_ws;
    const size_t ldsBytes = (size_t)RS * sizeof(float);   // 133,336 B

    static bool attrSet = false;
    if (!attrSet) {
        (void)hipFuncSetAttribute((const void*)nit_phase1,
                                  hipFuncAttributeMaxDynamicSharedMemorySize,
                                  (int)ldsBytes);
        attrSet = true;
    }

    const int cgc = (C + NXCD - 1) / NXCD;           // 10 for C=80
    const int grid1 = NXCD * RANGES * cgc;           // 240: 30 blocks/XCD <= 32 CUs
    nit_phase1<<<grid1, 1024, ldsBytes, stream>>>(row, col, x, partial,
                                                  N, E, chunkE, RS, C);

    int grid2 = (N + 255) / 256;
    nit_phase2<<<grid2, 256, 0, stream>>>(x, partial, w1, b1, w2, b2,
                                          out, N, C);
}